// Round 1
// baseline (3613.289 us; speedup 1.0000x reference)
//
#include <hip/hip_runtime.h>

#define N_NODES 50000
#define N_EDGES 800000
#define D_IN    64
#define D_HID   128

__global__ void k_deg(const int* __restrict__ rcv, float* __restrict__ deg) {
    int i = blockIdx.x * blockDim.x + threadIdx.x;
    if (i < N_EDGES) atomicAdd(&deg[rcv[i]], 1.0f);
}

__global__ void k_invdeg(const float* __restrict__ deg, float* __restrict__ inv) {
    int i = blockIdx.x * blockDim.x + threadIdx.x;
    if (i < N_NODES) {
        float d = deg[i];
        inv[i] = d > 0.0f ? 1.0f / d : 0.0f;
    }
}

// One thread per (edge, 4-feature chunk). Consecutive threads cover one edge's
// row -> coalesced float4 gather of h[sender], 4 atomicAdds to pooled[receiver].
template<int D>
__global__ void k_scatter(const float* __restrict__ h,
                          const float* __restrict__ w,
                          const int* __restrict__ snd,
                          const int* __restrict__ rcv,
                          float* __restrict__ pooled) {
    const int CH = D / 4;
    long tid = (long)blockIdx.x * blockDim.x + threadIdx.x;
    if (tid >= (long)N_EDGES * CH) return;
    int e = (int)(tid / CH);
    int c = (int)(tid % CH) * 4;
    float we = w[e];
    int s = snd[e], r = rcv[e];
    const float4 hv = *(const float4*)(h + (long)s * D + c);
    float* p = pooled + (long)r * D + c;
    atomicAdd(p + 0, hv.x * we);
    atomicAdd(p + 1, hv.y * we);
    atomicAdd(p + 2, hv.z * we);
    atomicAdd(p + 3, hv.w * we);
}

// One wave per node: pre = h*relu(1+eps) + pooled*inv_deg, then row @ W + b.
// Lane j accumulates output cols j and j+64. W rows broadcast via __shfl.
template<int DIN, int DOUT, bool RELU, bool WRITE_EMB>
__global__ void k_update_mlp(const float* __restrict__ h,
                             const float* __restrict__ pooled,
                             const float* __restrict__ invdeg,
                             const float* __restrict__ eps, int li,
                             const float* __restrict__ W,
                             const float* __restrict__ b,
                             float* __restrict__ out,
                             float* __restrict__ emb) {
    int wave = threadIdx.x >> 6;
    int lane = threadIdx.x & 63;
    int n = blockIdx.x * (blockDim.x >> 6) + wave;
    if (n >= N_NODES) return;

    float se = 1.0f + eps[li];
    se = se > 0.0f ? se : 0.0f;          // relu(1+eps)
    float id = invdeg[n];

    const float* hr = h + (long)n * DIN;
    const float* pr = pooled + (long)n * DIN;

    float pre[DIN / 64];
#pragma unroll
    for (int k = 0; k < DIN / 64; ++k) {
        int d = lane + 64 * k;
        pre[k] = hr[d] * se + pr[d] * id;
        if (WRITE_EMB) emb[(long)n * DIN + d] = pre[k];
    }

    float acc[DOUT / 64];
#pragma unroll
    for (int k = 0; k < DOUT / 64; ++k) acc[k] = b[lane + 64 * k];

#pragma unroll
    for (int d = 0; d < DIN; ++d) {
        float pd = __shfl(pre[d >> 6], d & 63);
#pragma unroll
        for (int k = 0; k < DOUT / 64; ++k)
            acc[k] += pd * W[d * DOUT + lane + 64 * k];
    }

    float* orow = out + (long)n * DOUT;
#pragma unroll
    for (int k = 0; k < DOUT / 64; ++k) {
        float v = acc[k];
        if (RELU) v = v > 0.0f ? v : 0.0f;
        orow[lane + 64 * k] = v;
    }
}

extern "C" void kernel_launch(void* const* d_in, const int* in_sizes, int n_in,
                              void* d_out, int out_size, void* d_ws, size_t ws_size,
                              hipStream_t stream) {
    const float* h0   = (const float*)d_in[0];   // 50000 x 64
    const float* wts  = (const float*)d_in[1];   // 800000
    const int*   snd  = (const int*)d_in[2];
    const int*   rcv  = (const int*)d_in[3];
    const float* W0   = (const float*)d_in[4];   // 64 x 128
    const float* b0   = (const float*)d_in[5];
    const float* W1   = (const float*)d_in[6];   // 128 x 128
    const float* b1   = (const float*)d_in[7];
    const float* W2   = (const float*)d_in[8];   // 128 x 128
    const float* b2   = (const float*)d_in[9];
    const float* eps  = (const float*)d_in[10];  // 3

    float* out0 = (float*)d_out;                 // node_embeddings (50000x128)
    float* out1 = out0 + (long)N_NODES * D_HID;  // final h        (50000x128)

    float* deg    = (float*)d_ws;                        // 50000
    float* inv    = deg + N_NODES;                       // 50000
    float* pooled = inv + N_NODES;                       // 50000*128

    // degree + inverse degree
    hipMemsetAsync(deg, 0, (size_t)N_NODES * sizeof(float), stream);
    k_deg<<<(N_EDGES + 255) / 256, 256, 0, stream>>>(rcv, deg);
    k_invdeg<<<(N_NODES + 255) / 256, 256, 0, stream>>>(deg, inv);

    // ---- layer 0: D_IN=64 -> D_HID=128, relu ----
    hipMemsetAsync(pooled, 0, (size_t)N_NODES * D_IN * sizeof(float), stream);
    {
        long nthr = (long)N_EDGES * (D_IN / 4);
        k_scatter<D_IN><<<(int)((nthr + 255) / 256), 256, 0, stream>>>(h0, wts, snd, rcv, pooled);
    }
    k_update_mlp<D_IN, D_HID, true, false><<<N_NODES / 4, 256, 0, stream>>>(
        h0, pooled, inv, eps, 0, W0, b0, out0, nullptr);

    // ---- layer 1: 128 -> 128, relu ----
    hipMemsetAsync(pooled, 0, (size_t)N_NODES * D_HID * sizeof(float), stream);
    {
        long nthr = (long)N_EDGES * (D_HID / 4);
        k_scatter<D_HID><<<(int)((nthr + 255) / 256), 256, 0, stream>>>(out0, wts, snd, rcv, pooled);
    }
    k_update_mlp<D_HID, D_HID, true, false><<<N_NODES / 4, 256, 0, stream>>>(
        out0, pooled, inv, eps, 1, W1, b1, out1, nullptr);

    // ---- layer 2: 128 -> 128, no relu; emit node_embeddings pre-MLP ----
    hipMemsetAsync(pooled, 0, (size_t)N_NODES * D_HID * sizeof(float), stream);
    {
        long nthr = (long)N_EDGES * (D_HID / 4);
        k_scatter<D_HID><<<(int)((nthr + 255) / 256), 256, 0, stream>>>(out1, wts, snd, rcv, pooled);
    }
    k_update_mlp<D_HID, D_HID, false, true><<<N_NODES / 4, 256, 0, stream>>>(
        out1, pooled, inv, eps, 2, W2, b2, out1, out0);
}

// Round 3
// 597.483 us; speedup vs baseline: 6.0475x; 6.0475x over previous
//
#include <hip/hip_runtime.h>

#define N_NODES 50000
#define N_EDGES 800000
#define D_IN    64
#define D_HID   128

#define SCAN_THREADS 1024
#define SCAN_CHUNK   ((N_NODES + SCAN_THREADS - 1) / SCAN_THREADS)   // 49

// ---- CSR build ----
__global__ void k_count(const int* __restrict__ rcv, int* __restrict__ deg) {
    int i = blockIdx.x * blockDim.x + threadIdx.x;
    if (i < N_EDGES) atomicAdd(&deg[rcv[i]], 1);
}

// Single-block exclusive scan over 50k degrees -> off[], cursor[], inv_deg[].
__global__ void k_scan(const int* __restrict__ deg,
                       int* __restrict__ off, int* __restrict__ cursor,
                       float* __restrict__ inv) {
    __shared__ int ssum[SCAN_THREADS];
    int t = threadIdx.x;
    int lo = t * SCAN_CHUNK;
    int hi = lo + SCAN_CHUNK; if (hi > N_NODES) hi = N_NODES;

    int s = 0;
    for (int i = lo; i < hi; ++i) s += deg[i];
    ssum[t] = s;
    __syncthreads();
    // Hillis-Steele inclusive scan in LDS
    for (int d = 1; d < SCAN_THREADS; d <<= 1) {
        int v = (t >= d) ? ssum[t - d] : 0;
        __syncthreads();
        ssum[t] += v;
        __syncthreads();
    }
    int run = (t > 0) ? ssum[t - 1] : 0;
    for (int i = lo; i < hi; ++i) {
        off[i] = run; cursor[i] = run;
        int d = deg[i];
        inv[i] = d > 0 ? 1.0f / (float)d : 0.0f;
        run += d;
    }
    if (t == SCAN_THREADS - 1) off[N_NODES] = run;   // == N_EDGES
}

__global__ void k_fill(const int* __restrict__ snd, const int* __restrict__ rcv,
                       const float* __restrict__ w,
                       int* __restrict__ cursor,
                       int* __restrict__ e_snd, float* __restrict__ e_w) {
    int i = blockIdx.x * blockDim.x + threadIdx.x;
    if (i >= N_EDGES) return;
    int r = rcv[i];
    int p = atomicAdd(&cursor[r], 1);
    e_snd[p] = snd[i];
    e_w[p]   = w[i];
}

// ---- fused layer: per-node gather + residual update (+ optional MLP) ----
// One wave per node; lane l holds feature(s) l (+64k). Gather over the node's
// CSR edge range accumulates in registers; MLP via __shfl row-broadcast of W.
template<int DIN, int DOUT, bool RELU, bool DO_MLP>
__global__ void k_layer(const float* __restrict__ h,
                        const int* __restrict__ off,
                        const int* __restrict__ e_snd,
                        const float* __restrict__ e_w,
                        const float* __restrict__ inv,
                        const float* __restrict__ eps, int li,
                        const float* __restrict__ W,
                        const float* __restrict__ b,
                        float* __restrict__ out) {
    constexpr int K = DIN / 64;
    int wave = threadIdx.x >> 6;
    int lane = threadIdx.x & 63;
    int n = blockIdx.x * (blockDim.x >> 6) + wave;
    if (n >= N_NODES) return;

    float pool[K];
#pragma unroll
    for (int k = 0; k < K; ++k) pool[k] = 0.0f;

    int e0 = off[n], e1 = off[n + 1];
    int e = e0;
    for (; e + 1 < e1; e += 2) {          // unroll-2 for load ILP
        int s0 = e_snd[e], s1 = e_snd[e + 1];
        float w0 = e_w[e], w1 = e_w[e + 1];
        const float* p0 = h + (long)s0 * DIN;
        const float* p1 = h + (long)s1 * DIN;
        float a0[K], a1[K];
#pragma unroll
        for (int k = 0; k < K; ++k) { a0[k] = p0[lane + 64 * k]; a1[k] = p1[lane + 64 * k]; }
#pragma unroll
        for (int k = 0; k < K; ++k) pool[k] += a0[k] * w0 + a1[k] * w1;
    }
    if (e < e1) {
        int s0 = e_snd[e]; float w0 = e_w[e];
        const float* p0 = h + (long)s0 * DIN;
#pragma unroll
        for (int k = 0; k < K; ++k) pool[k] += p0[lane + 64 * k] * w0;
    }

    float se = 1.0f + eps[li];
    se = se > 0.0f ? se : 0.0f;           // relu(1+eps)
    float id = inv[n];
    const float* hr = h + (long)n * DIN;

    float pre[K];
#pragma unroll
    for (int k = 0; k < K; ++k) pre[k] = hr[lane + 64 * k] * se + pool[k] * id;

    if (!DO_MLP) {
        float* orow = out + (long)n * DIN;
#pragma unroll
        for (int k = 0; k < K; ++k) orow[lane + 64 * k] = pre[k];
        return;
    }

    float acc[DOUT / 64];
#pragma unroll
    for (int k = 0; k < DOUT / 64; ++k) acc[k] = b[lane + 64 * k];
#pragma unroll
    for (int d = 0; d < DIN; ++d) {
        float pd = __shfl(pre[d >> 6], d & 63);
#pragma unroll
        for (int k = 0; k < DOUT / 64; ++k)
            acc[k] += pd * W[d * DOUT + lane + 64 * k];
    }
    float* orow = out + (long)n * DOUT;
#pragma unroll
    for (int k = 0; k < DOUT / 64; ++k) {
        float v = acc[k];
        if (RELU) v = v > 0.0f ? v : 0.0f;
        orow[lane + 64 * k] = v;
    }
}

// ---- standalone per-row MLP (layer-2 tail; in-place-safe per row) ----
template<int DIN, int DOUT, bool RELU>
__global__ void k_mlp(const float* __restrict__ h,
                      const float* __restrict__ W,
                      const float* __restrict__ b,
                      float* __restrict__ out) {
    int wave = threadIdx.x >> 6;
    int lane = threadIdx.x & 63;
    int n = blockIdx.x * (blockDim.x >> 6) + wave;
    if (n >= N_NODES) return;

    const float* hr = h + (long)n * DIN;
    float pre[DIN / 64];
#pragma unroll
    for (int k = 0; k < DIN / 64; ++k) pre[k] = hr[lane + 64 * k];

    float acc[DOUT / 64];
#pragma unroll
    for (int k = 0; k < DOUT / 64; ++k) acc[k] = b[lane + 64 * k];
#pragma unroll
    for (int d = 0; d < DIN; ++d) {
        float pd = __shfl(pre[d >> 6], d & 63);
#pragma unroll
        for (int k = 0; k < DOUT / 64; ++k)
            acc[k] += pd * W[d * DOUT + lane + 64 * k];
    }
    float* orow = out + (long)n * DOUT;
#pragma unroll
    for (int k = 0; k < DOUT / 64; ++k) {
        float v = acc[k];
        if (RELU) v = v > 0.0f ? v : 0.0f;
        orow[lane + 64 * k] = v;
    }
}

extern "C" void kernel_launch(void* const* d_in, const int* in_sizes, int n_in,
                              void* d_out, int out_size, void* d_ws, size_t ws_size,
                              hipStream_t stream) {
    const float* h0  = (const float*)d_in[0];
    const float* wts = (const float*)d_in[1];
    const int*   snd = (const int*)d_in[2];
    const int*   rcv = (const int*)d_in[3];
    const float* W0  = (const float*)d_in[4];
    const float* b0  = (const float*)d_in[5];
    const float* W1  = (const float*)d_in[6];
    const float* b1  = (const float*)d_in[7];
    const float* W2  = (const float*)d_in[8];
    const float* b2  = (const float*)d_in[9];
    const float* eps = (const float*)d_in[10];

    float* out0 = (float*)d_out;                  // node_embeddings
    float* out1 = out0 + (long)N_NODES * D_HID;   // final h

    // workspace: deg|off|cursor|inv|e_snd|e_w  (~7.2 MB)
    int*   deg    = (int*)d_ws;
    int*   off    = deg + N_NODES;                // N_NODES+1
    int*   cursor = off + N_NODES + 1;
    float* inv    = (float*)(cursor + N_NODES);
    int*   e_snd  = (int*)(inv + N_NODES);
    float* e_w    = (float*)(e_snd + N_EDGES);

    hipMemsetAsync(deg, 0, (size_t)N_NODES * sizeof(int), stream);
    k_count<<<(N_EDGES + 255) / 256, 256, 0, stream>>>(rcv, deg);
    k_scan<<<1, SCAN_THREADS, 0, stream>>>(deg, off, cursor, inv);
    k_fill<<<(N_EDGES + 255) / 256, 256, 0, stream>>>(snd, rcv, wts, cursor, e_snd, e_w);

    // L0: h0(64) -> out0(128), relu
    k_layer<D_IN, D_HID, true, true><<<N_NODES / 4, 256, 0, stream>>>(
        h0, off, e_snd, e_w, inv, eps, 0, W0, b0, out0);
    // L1: out0 -> out1, relu
    k_layer<D_HID, D_HID, true, true><<<N_NODES / 4, 256, 0, stream>>>(
        out0, off, e_snd, e_w, inv, eps, 1, W1, b1, out1);
    // L2a: gather+update only: out1 -> out0 (= node_embeddings)
    k_layer<D_HID, D_HID, false, false><<<N_NODES / 4, 256, 0, stream>>>(
        out1, off, e_snd, e_w, inv, eps, 2, nullptr, nullptr, out0);
    // L2b: final MLP (no relu): out0 -> out1
    k_mlp<D_HID, D_HID, false><<<N_NODES / 4, 256, 0, stream>>>(out0, W2, b2, out1);
}